// Round 5
// baseline (3574.418 us; speedup 1.0000x reference)
//
#include <hip/hip_runtime.h>
#include <hip/hip_bf16.h>

#define BB 8
#define NN 2048
#define DD 128
#define NSTEPS 16
#define DT_F 0.1f
#define TWO_PI_F 6.283185307179586f
#define NBLK 256   // persist grid: 1 block per CU

typedef short short8 __attribute__((ext_vector_type(8)));
typedef float floatx4 __attribute__((ext_vector_type(4)));

// ---------------- K0: split fp32 embeddings into bf16 hi/lo ----------------
// Also zeroes the grid-barrier counter for this launch (graph-replay safe).
__global__ void split_kernel(const float* __restrict__ e,
                             __hip_bfloat16* __restrict__ hi,
                             __hip_bfloat16* __restrict__ lo,
                             unsigned* __restrict__ bar) {
    int i = blockIdx.x * 256 + threadIdx.x;
    if (i == 0) bar[0] = 0u;
    float x = e[i];
    __hip_bfloat16 h = __float2bfloat16(x);
    hi[i] = h;
    lo[i] = __float2bfloat16(x - __bfloat162float(h));
}

// ---------------- K1: coupling matrix via bf16 MFMA (hi/lo split) ----------
// exp(-acosh(x)) = 1/(x + sqrt(x^2-1)); /1.000001 tau factor <=1e-5 rel.
#define LDP 136

__launch_bounds__(256, 2)
__global__ void coupling_kernel(const __hip_bfloat16* __restrict__ Ehi,
                                const __hip_bfloat16* __restrict__ Elo,
                                __hip_bfloat16* __restrict__ C) {
    __shared__ __hip_bfloat16 Ah[64 * LDP];
    __shared__ __hip_bfloat16 Al[64 * LDP];
    __shared__ __hip_bfloat16 Bh[64 * LDP];
    __shared__ __hip_bfloat16 Bl[64 * LDP];

    const int b  = blockIdx.z;
    const int n0 = blockIdx.y * 64;
    const int m0 = blockIdx.x * 64;
    const int tid = threadIdx.x;

    const __hip_bfloat16* aHsrc = Ehi + ((size_t)b * NN + n0) * DD;
    const __hip_bfloat16* aLsrc = Elo + ((size_t)b * NN + n0) * DD;
    const __hip_bfloat16* bHsrc = Ehi + ((size_t)b * NN + m0) * DD;
    const __hip_bfloat16* bLsrc = Elo + ((size_t)b * NN + m0) * DD;

    #pragma unroll
    for (int i = 0; i < 4; ++i) {
        int c   = tid + 256 * i;
        int row = c >> 4;
        int col = (c & 15) * 8;
        *(uint4*)(Ah + row * LDP + col) = *(const uint4*)(aHsrc + row * DD + col);
        *(uint4*)(Al + row * LDP + col) = *(const uint4*)(aLsrc + row * DD + col);
        *(uint4*)(Bh + row * LDP + col) = *(const uint4*)(bHsrc + row * DD + col);
        *(uint4*)(Bl + row * LDP + col) = *(const uint4*)(bLsrc + row * DD + col);
    }
    __syncthreads();

    const int wave = tid >> 6;
    const int lane = tid & 63;
    const int l16  = lane & 15;
    const int quad = lane >> 4;

    floatx4 acc[4] = {floatx4{0,0,0,0}, floatx4{0,0,0,0},
                      floatx4{0,0,0,0}, floatx4{0,0,0,0}};

    const int arow = wave * 16 + l16;
    #pragma unroll
    for (int kt = 0; kt < 4; ++kt) {
        const int ko = kt * 32 + quad * 8;
        short8 ah = *(const short8*)(Ah + arow * LDP + ko);
        short8 al = *(const short8*)(Al + arow * LDP + ko);
        #pragma unroll
        for (int c = 0; c < 4; ++c) {
            const int brow = c * 16 + l16;
            short8 bh = *(const short8*)(Bh + brow * LDP + ko);
            short8 bl = *(const short8*)(Bl + brow * LDP + ko);
            acc[c] = __builtin_amdgcn_mfma_f32_16x16x32_bf16(ah, bh, acc[c], 0, 0, 0);
            acc[c] = __builtin_amdgcn_mfma_f32_16x16x32_bf16(ah, bl, acc[c], 0, 0, 0);
            acc[c] = __builtin_amdgcn_mfma_f32_16x16x32_bf16(al, bh, acc[c], 0, 0, 0);
        }
    }

    float tn2[4];
    #pragma unroll
    for (int i = 0; i < 4; ++i) {
        int r = wave * 16 + quad * 4 + i;
        tn2[i] = 2.0f * (__bfloat162float(Ah[r * LDP]) + __bfloat162float(Al[r * LDP]));
    }
    #pragma unroll
    for (int c = 0; c < 4; ++c) {
        int br = c * 16 + l16;
        float tm = __bfloat162float(Bh[br * LDP]) + __bfloat162float(Bl[br * LDP]);
        size_t base = ((size_t)b * NN + n0 + wave * 16 + quad * 4) * (size_t)NN
                      + m0 + c * 16 + l16;
        #pragma unroll
        for (int i = 0; i < 4; ++i) {
            float g   = acc[c][i];
            float arg = fmaxf(fmaf(tn2[i], tm, -g), 1.0f + 1e-7f);
            float s   = sqrtf(fmaf(arg, arg, -1.0f));
            float cp  = __builtin_amdgcn_rcpf(arg + s);
            C[base + (size_t)i * NN] = __float2bfloat16(fminf(cp, 1.0f));
        }
    }
}

// ---------------- K2: persistent cooperative kernel — all 16 steps ---------
// 256 blocks (1/CU) x 1024 threads (16 waves, 4/SIMD). Each wave owns 4 rows
// of C in registers: 4 rows x 32 bf16/lane = 64 VGPRs.
// Rounds 1-4: VGPR_Count pinned at exactly 128 regardless of launch_bounds
// => the allocator's register budget is 128 (4 waves/EU target) and nothing
// declarative moves it. With 512 threads the C footprint alone was 128 regs
// => guaranteed spill (FETCH 1.4 GB at scratch BW). Fix: 1024 threads/block
// halves per-lane C to 64 regs; total demand ~116 < 128 budget. 4 waves/SIMD
// is also the HW max at 128 regs, so budget and hardware now agree.

#define CSPAD(m) ((m) + ((m) >> 3))   // +1 float2 pad per 8: lane stride 72B

__device__ __forceinline__ void grid_barrier(unsigned* bar, unsigned want) {
    __threadfence();          // release this block's theta writes (all threads)
    __syncthreads();          // all threads' stores issued before arrival
    if (threadIdx.x == 0) {
        __hip_atomic_fetch_add(bar, 1u, __ATOMIC_RELEASE, __HIP_MEMORY_SCOPE_AGENT);
        while (__hip_atomic_load(bar, __ATOMIC_ACQUIRE, __HIP_MEMORY_SCOPE_AGENT) < want)
            __builtin_amdgcn_s_sleep(2);
    }
    __syncthreads();          // everyone waits for tid0's pass
    __threadfence();          // acquire: invalidate stale cached theta
}

__launch_bounds__(1024)
__global__ void persist_kernel(const __hip_bfloat16* __restrict__ C,
                               const float* __restrict__ theta0,
                               float* __restrict__ thA,
                               float* __restrict__ thB,
                               float* __restrict__ outp,
                               const float* __restrict__ omega,
                               unsigned* __restrict__ bar) {
    __shared__ float2 cs[NN + (NN >> 3)];   // 2304 float2 = 18 KiB

    const int tid  = threadIdx.x;
    const int lane = tid & 63;
    const int wave = tid >> 6;              // 0..15
    const int b    = blockIdx.x >> 5;       // batch
    const int rg   = blockIdx.x & 31;       // row group within batch
    const int row0 = rg * 64 + wave * 4;    // first of this wave's 4 rows

    // ---- load this wave's 4 C-rows into registers (coalesced 1KB/instr) ----
    uint4 creg[4][4];
    {
        const __hip_bfloat16* Cw = C + ((size_t)b * NN + row0) * (size_t)NN + lane * 8;
        #pragma unroll
        for (int r = 0; r < 4; ++r) {
            #pragma unroll
            for (int j = 0; j < 4; ++j)
                creg[r][j] = *(const uint4*)(Cw + (size_t)r * NN + j * 512);
        }
    }

    const float* cur = theta0;
    for (int s = 0; s < NSTEPS; ++s) {
        const float* th_b = cur + b * NN;

        // ---- cos/sin table for this batch's 2048 thetas (padded LDS) ----
        #pragma unroll
        for (int i = 0; i < 2; ++i) {
            int m = tid + 1024 * i;
            float sv, cv;
            __sincosf(th_b[m], &sv, &cv);
            cs[CSPAD(m)] = make_float2(cv, sv);
        }
        __syncthreads();

        // ---- MAC: j-tile outer (16 cs regs live), rows inner ----
        float a0[4], a1[4], s0[4], s1[4];
        #pragma unroll
        for (int r = 0; r < 4; ++r) { a0[r] = a1[r] = s0[r] = s1[r] = 0.f; }

        #pragma unroll
        for (int j = 0; j < 4; ++j) {
            float cc8[8], ss8[8];
            int p0 = CSPAD(j * 512 + lane * 8);
            #pragma unroll
            for (int i = 0; i < 8; ++i) {
                float2 v = cs[p0 + i];
                cc8[i] = v.x;
                ss8[i] = v.y;
            }
            #pragma unroll
            for (int r = 0; r < 4; ++r) {
                unsigned u[4] = {creg[r][j].x, creg[r][j].y, creg[r][j].z, creg[r][j].w};
                #pragma unroll
                for (int k = 0; k < 4; ++k) {
                    float f0 = __uint_as_float(u[k] << 16);
                    float f1 = __uint_as_float(u[k] & 0xffff0000u);
                    a0[r] = fmaf(f0, cc8[2 * k],     a0[r]);
                    s0[r] = fmaf(f0, ss8[2 * k],     s0[r]);
                    a1[r] = fmaf(f1, cc8[2 * k + 1], a1[r]);
                    s1[r] = fmaf(f1, ss8[2 * k + 1], s1[r]);
                }
            }
        }

        float sumc[4], sums[4];
        #pragma unroll
        for (int r = 0; r < 4; ++r) {
            sumc[r] = a0[r] + a1[r];
            sums[r] = s0[r] + s1[r];
        }

        // ---- 64-lane butterfly reduce (same order as before) ----
        #pragma unroll
        for (int r = 0; r < 4; ++r) {
            #pragma unroll
            for (int off = 32; off >= 1; off >>= 1) {
                sumc[r] += __shfl_xor(sumc[r], off, 64);
                sums[r] += __shfl_xor(sums[r], off, 64);
            }
        }

        // ---- theta update for this wave's 4 rows ----
        float* nxt = (s == NSTEPS - 1) ? outp : ((s & 1) ? thB : thA);
        #pragma unroll
        for (int r = 0; r < 4; ++r) {
            if (lane == r) {
                int n = row0 + r;
                float2 csn = cs[CSPAD(n)];
                float sum  = csn.y * sumc[r] - csn.x * sums[r];
                float th   = th_b[n];
                float dth  = omega[n] + (1.0f / NN) * sum;
                nxt[b * NN + n] = fmodf(th + DT_F * dth, TWO_PI_F);
            }
        }

        if (s != NSTEPS - 1) {
            grid_barrier(bar, (unsigned)NBLK * (unsigned)(s + 1));
            cur = (s & 1) ? thB : thA;
        }
    }
}

// ---------------- launch ----------------------------------------------------
extern "C" void kernel_launch(void* const* d_in, const int* in_sizes, int n_in,
                              void* d_out, int out_size, void* d_ws, size_t ws_size,
                              hipStream_t stream) {
    const float* theta0 = (const float*)d_in[0];
    const float* emb    = (const float*)d_in[1];
    const float* omega  = (const float*)d_in[2];
    float* out = (float*)d_out;

    char* ws = (char*)d_ws;
    __hip_bfloat16* C   = (__hip_bfloat16*)ws;                       // 64 MiB
    __hip_bfloat16* Ehi = (__hip_bfloat16*)(ws + 67108864);          // 4 MiB
    __hip_bfloat16* Elo = (__hip_bfloat16*)(ws + 71303168);          // 4 MiB
    float* tA = (float*)(ws + 75497472);                             // 64 KiB
    float* tB = (float*)(ws + 75563008);                             // 64 KiB
    unsigned* bar = (unsigned*)(ws + 75628544);                      // 4 B

    split_kernel<<<(BB * NN * DD) / 256, 256, 0, stream>>>(emb, Ehi, Elo, bar);

    dim3 g1(NN / 64, NN / 64, BB);
    coupling_kernel<<<g1, 256, 0, stream>>>(Ehi, Elo, C);

    const __hip_bfloat16* Cc = C;
    void* kargs[] = { (void*)&Cc, (void*)&theta0, (void*)&tA, (void*)&tB,
                      (void*)&out, (void*)&omega, (void*)&bar };
    hipLaunchCooperativeKernel((void*)persist_kernel,
                               dim3(NBLK), dim3(1024),
                               kargs, 0, stream);
}

// Round 7
// 3282.455 us; speedup vs baseline: 1.0889x; 1.0889x over previous
//
#include <hip/hip_runtime.h>
#include <hip/hip_bf16.h>

#define BB 8
#define NN 2048
#define DD 128
#define NSTEPS 16
#define DT_F 0.1f
#define TWO_PI_F 6.283185307179586f
#define PBLK 256   // persist grid: 256 blocks (1/CU) — proven coop shape

typedef short short8 __attribute__((ext_vector_type(8)));
typedef float floatx4 __attribute__((ext_vector_type(4)));

// ---------------- K0: split fp32 embeddings into bf16 hi/lo ----------------
// Also zeroes both grid-barrier counters for this launch (graph-replay safe).
__global__ void split_kernel(const float* __restrict__ e,
                             __hip_bfloat16* __restrict__ hi,
                             __hip_bfloat16* __restrict__ lo,
                             unsigned* __restrict__ bar) {
    int i = blockIdx.x * 256 + threadIdx.x;
    if (i == 0) { bar[0] = 0u; bar[1] = 0u; }
    float x = e[i];
    __hip_bfloat16 h = __float2bfloat16(x);
    hi[i] = h;
    lo[i] = __float2bfloat16(x - __bfloat162float(h));
}

// ---------------- K1: coupling matrix via bf16 MFMA (hi/lo split) ----------
// exp(-acosh(x)) = 1/(x + sqrt(x^2-1)); /1.000001 tau factor <=1e-5 rel.
#define LDP 136

__launch_bounds__(256, 2)
__global__ void coupling_kernel(const __hip_bfloat16* __restrict__ Ehi,
                                const __hip_bfloat16* __restrict__ Elo,
                                __hip_bfloat16* __restrict__ C) {
    __shared__ __hip_bfloat16 Ah[64 * LDP];
    __shared__ __hip_bfloat16 Al[64 * LDP];
    __shared__ __hip_bfloat16 Bh[64 * LDP];
    __shared__ __hip_bfloat16 Bl[64 * LDP];

    const int b  = blockIdx.z;
    const int n0 = blockIdx.y * 64;
    const int m0 = blockIdx.x * 64;
    const int tid = threadIdx.x;

    const __hip_bfloat16* aHsrc = Ehi + ((size_t)b * NN + n0) * DD;
    const __hip_bfloat16* aLsrc = Elo + ((size_t)b * NN + n0) * DD;
    const __hip_bfloat16* bHsrc = Ehi + ((size_t)b * NN + m0) * DD;
    const __hip_bfloat16* bLsrc = Elo + ((size_t)b * NN + m0) * DD;

    #pragma unroll
    for (int i = 0; i < 4; ++i) {
        int c   = tid + 256 * i;
        int row = c >> 4;
        int col = (c & 15) * 8;
        *(uint4*)(Ah + row * LDP + col) = *(const uint4*)(aHsrc + row * DD + col);
        *(uint4*)(Al + row * LDP + col) = *(const uint4*)(aLsrc + row * DD + col);
        *(uint4*)(Bh + row * LDP + col) = *(const uint4*)(bHsrc + row * DD + col);
        *(uint4*)(Bl + row * LDP + col) = *(const uint4*)(bLsrc + row * DD + col);
    }
    __syncthreads();

    const int wave = tid >> 6;
    const int lane = tid & 63;
    const int l16  = lane & 15;
    const int quad = lane >> 4;

    floatx4 acc[4] = {floatx4{0,0,0,0}, floatx4{0,0,0,0},
                      floatx4{0,0,0,0}, floatx4{0,0,0,0}};

    const int arow = wave * 16 + l16;
    #pragma unroll
    for (int kt = 0; kt < 4; ++kt) {
        const int ko = kt * 32 + quad * 8;
        short8 ah = *(const short8*)(Ah + arow * LDP + ko);
        short8 al = *(const short8*)(Al + arow * LDP + ko);
        #pragma unroll
        for (int c = 0; c < 4; ++c) {
            const int brow = c * 16 + l16;
            short8 bh = *(const short8*)(Bh + brow * LDP + ko);
            short8 bl = *(const short8*)(Bl + brow * LDP + ko);
            acc[c] = __builtin_amdgcn_mfma_f32_16x16x32_bf16(ah, bh, acc[c], 0, 0, 0);
            acc[c] = __builtin_amdgcn_mfma_f32_16x16x32_bf16(ah, bl, acc[c], 0, 0, 0);
            acc[c] = __builtin_amdgcn_mfma_f32_16x16x32_bf16(al, bh, acc[c], 0, 0, 0);
        }
    }

    float tn2[4];
    #pragma unroll
    for (int i = 0; i < 4; ++i) {
        int r = wave * 16 + quad * 4 + i;
        tn2[i] = 2.0f * (__bfloat162float(Ah[r * LDP]) + __bfloat162float(Al[r * LDP]));
    }
    #pragma unroll
    for (int c = 0; c < 4; ++c) {
        int br = c * 16 + l16;
        float tm = __bfloat162float(Bh[br * LDP]) + __bfloat162float(Bl[br * LDP]);
        size_t base = ((size_t)b * NN + n0 + wave * 16 + quad * 4) * (size_t)NN
                      + m0 + c * 16 + l16;
        #pragma unroll
        for (int i = 0; i < 4; ++i) {
            float g   = acc[c][i];
            float arg = fmaxf(fmaf(tn2[i], tm, -g), 1.0f + 1e-7f);
            float s   = sqrtf(fmaf(arg, arg, -1.0f));
            float cp  = __builtin_amdgcn_rcpf(arg + s);
            C[base + (size_t)i * NN] = __float2bfloat16(fminf(cp, 1.0f));
        }
    }
}

// ---------------- K2: persistent cooperative kernel — 16 steps, 4 batches --
// Two sequential cooperative launches of 256 blocks x 256 threads (4 waves),
// each launch owns batches [b0, b0+4). Per block: 32 rows (64 blocks/batch);
// per wave: 8 rows of C in registers (8 x 32 bf16/lane = 128 VGPRs).
// Why this shape: allocator rule measured in rounds 1-5 is cap = 1024/waves
// (512thr->128, 1024thr->64, launch_bounds ignored) => 4-wave block caps at
// 256 VGPRs; demand ~196 fits. 256-block coop launches are the proven-to-run
// shape (rounds 3-5); round 6's 512-block launch silently failed its
// occupancy gate (output stayed zeroed => absmax 6.28 = max|ref|).

#define CSPAD(m) ((m) + ((m) >> 3))   // +1 float2 pad per 8: lane stride 72B

__device__ __forceinline__ void grid_barrier(unsigned* bar, unsigned want) {
    __threadfence();          // release this block's theta writes (all threads)
    __syncthreads();          // all threads' stores issued before arrival
    if (threadIdx.x == 0) {
        __hip_atomic_fetch_add(bar, 1u, __ATOMIC_RELEASE, __HIP_MEMORY_SCOPE_AGENT);
        while (__hip_atomic_load(bar, __ATOMIC_ACQUIRE, __HIP_MEMORY_SCOPE_AGENT) < want)
            __builtin_amdgcn_s_sleep(2);
    }
    __syncthreads();          // everyone waits for tid0's pass
    __threadfence();          // acquire: invalidate stale cached theta
}

__launch_bounds__(256, 2)
__global__ void persist_kernel(const __hip_bfloat16* __restrict__ C,
                               const float* __restrict__ theta0,
                               float* __restrict__ thA,
                               float* __restrict__ thB,
                               float* __restrict__ outp,
                               const float* __restrict__ omega,
                               unsigned* __restrict__ bar,
                               int b0) {
    __shared__ float2 cs[NN + (NN >> 3)];   // 2304 float2 = 18 KiB

    const int tid  = threadIdx.x;
    const int lane = tid & 63;
    const int wave = tid >> 6;              // 0..3
    const int b    = b0 + (blockIdx.x >> 6);// batch (64 blocks per batch)
    const int rg   = blockIdx.x & 63;       // row group within batch
    const int row0 = rg * 32 + wave * 8;    // first of this wave's 8 rows

    // ---- load this wave's 8 C-rows into registers (coalesced 1KB/instr) ----
    uint4 creg[8][4];
    {
        const __hip_bfloat16* Cw = C + ((size_t)b * NN + row0) * (size_t)NN + lane * 8;
        #pragma unroll
        for (int r = 0; r < 8; ++r) {
            #pragma unroll
            for (int j = 0; j < 4; ++j)
                creg[r][j] = *(const uint4*)(Cw + (size_t)r * NN + j * 512);
        }
    }

    const float* cur = theta0;
    for (int s = 0; s < NSTEPS; ++s) {
        const float* th_b = cur + b * NN;

        // ---- cos/sin table for this batch's 2048 thetas (padded LDS) ----
        #pragma unroll
        for (int i = 0; i < 8; ++i) {
            int m = tid + 256 * i;
            float sv, cv;
            __sincosf(th_b[m], &sv, &cv);
            cs[CSPAD(m)] = make_float2(cv, sv);
        }
        __syncthreads();

        // ---- MAC: j-tile outer (16 cs regs live), rows inner ----
        float a0[8], a1[8], s0[8], s1[8];
        #pragma unroll
        for (int r = 0; r < 8; ++r) { a0[r] = a1[r] = s0[r] = s1[r] = 0.f; }

        #pragma unroll
        for (int j = 0; j < 4; ++j) {
            float cc8[8], ss8[8];
            int p0 = CSPAD(j * 512 + lane * 8);
            #pragma unroll
            for (int i = 0; i < 8; ++i) {
                float2 v = cs[p0 + i];
                cc8[i] = v.x;
                ss8[i] = v.y;
            }
            #pragma unroll
            for (int r = 0; r < 8; ++r) {
                unsigned u[4] = {creg[r][j].x, creg[r][j].y, creg[r][j].z, creg[r][j].w};
                #pragma unroll
                for (int k = 0; k < 4; ++k) {
                    float f0 = __uint_as_float(u[k] << 16);
                    float f1 = __uint_as_float(u[k] & 0xffff0000u);
                    a0[r] = fmaf(f0, cc8[2 * k],     a0[r]);
                    s0[r] = fmaf(f0, ss8[2 * k],     s0[r]);
                    a1[r] = fmaf(f1, cc8[2 * k + 1], a1[r]);
                    s1[r] = fmaf(f1, ss8[2 * k + 1], s1[r]);
                }
            }
        }

        float sumc[8], sums[8];
        #pragma unroll
        for (int r = 0; r < 8; ++r) {
            sumc[r] = a0[r] + a1[r];
            sums[r] = s0[r] + s1[r];
        }

        // ---- 64-lane butterfly reduce (same order as before) ----
        #pragma unroll
        for (int r = 0; r < 8; ++r) {
            #pragma unroll
            for (int off = 32; off >= 1; off >>= 1) {
                sumc[r] += __shfl_xor(sumc[r], off, 64);
                sums[r] += __shfl_xor(sums[r], off, 64);
            }
        }

        // ---- theta update for this wave's 8 rows ----
        float* nxt = (s == NSTEPS - 1) ? outp : ((s & 1) ? thB : thA);
        #pragma unroll
        for (int r = 0; r < 8; ++r) {
            if (lane == r) {
                int n = row0 + r;
                float2 csn = cs[CSPAD(n)];
                float sum  = csn.y * sumc[r] - csn.x * sums[r];
                float th   = th_b[n];
                float dth  = omega[n] + (1.0f / NN) * sum;
                nxt[b * NN + n] = fmodf(th + DT_F * dth, TWO_PI_F);
            }
        }

        if (s != NSTEPS - 1) {
            grid_barrier(bar, (unsigned)PBLK * (unsigned)(s + 1));
            cur = (s & 1) ? thB : thA;
        }
    }
}

// ---------------- launch ----------------------------------------------------
extern "C" void kernel_launch(void* const* d_in, const int* in_sizes, int n_in,
                              void* d_out, int out_size, void* d_ws, size_t ws_size,
                              hipStream_t stream) {
    const float* theta0 = (const float*)d_in[0];
    const float* emb    = (const float*)d_in[1];
    const float* omega  = (const float*)d_in[2];
    float* out = (float*)d_out;

    char* ws = (char*)d_ws;
    __hip_bfloat16* C   = (__hip_bfloat16*)ws;                       // 64 MiB
    __hip_bfloat16* Ehi = (__hip_bfloat16*)(ws + 67108864);          // 4 MiB
    __hip_bfloat16* Elo = (__hip_bfloat16*)(ws + 71303168);          // 4 MiB
    float* tA = (float*)(ws + 75497472);                             // 64 KiB
    float* tB = (float*)(ws + 75563008);                             // 64 KiB
    unsigned* bar = (unsigned*)(ws + 75628544);                      // 8 B

    split_kernel<<<(BB * NN * DD) / 256, 256, 0, stream>>>(emb, Ehi, Elo, bar);

    dim3 g1(NN / 64, NN / 64, BB);
    coupling_kernel<<<g1, 256, 0, stream>>>(Ehi, Elo, C);

    const __hip_bfloat16* Cc = C;
    static int b0s[2] = {0, 4};
    unsigned* barp[2] = { bar, bar + 1 };
    void* kargs0[] = { (void*)&Cc, (void*)&theta0, (void*)&tA, (void*)&tB,
                       (void*)&out, (void*)&omega, (void*)&barp[0], (void*)&b0s[0] };
    void* kargs1[] = { (void*)&Cc, (void*)&theta0, (void*)&tA, (void*)&tB,
                       (void*)&out, (void*)&omega, (void*)&barp[1], (void*)&b0s[1] };
    hipLaunchCooperativeKernel((void*)persist_kernel, dim3(PBLK), dim3(256),
                               kargs0, 0, stream);
    hipLaunchCooperativeKernel((void*)persist_kernel, dim3(PBLK), dim3(256),
                               kargs1, 0, stream);
}

// Round 8
// 1548.121 us; speedup vs baseline: 2.3089x; 2.1203x over previous
//
#include <hip/hip_runtime.h>
#include <hip/hip_bf16.h>

#define BB 8
#define NN 2048
#define DD 128
#define NSTEPS 16
#define DT_F 0.1f
#define TWO_PI_F 6.283185307179586f
#define PBLK 256            // persist grid: 256 blocks (1/CU) — proven coop shape
#define BLK_PER_BATCH 32    // 32 blocks x 64 rows = 2048 rows per batch
#define INV255 (1.0f / 255.0f)

typedef short short8 __attribute__((ext_vector_type(8)));
typedef float floatx4 __attribute__((ext_vector_type(4)));

// ---------------- K0: split fp32 embeddings into bf16 hi/lo ----------------
// Also zeroes the per-batch barrier counters (graph-replay safe).
__global__ void split_kernel(const float* __restrict__ e,
                             __hip_bfloat16* __restrict__ hi,
                             __hip_bfloat16* __restrict__ lo,
                             unsigned* __restrict__ bar) {
    int i = blockIdx.x * 256 + threadIdx.x;
    if (i < 512) bar[i] = 0u;
    float x = e[i];
    __hip_bfloat16 h = __float2bfloat16(x);
    hi[i] = h;
    lo[i] = __float2bfloat16(x - __bfloat162float(h));
}

// ---------------- K1: coupling matrix via bf16 MFMA (hi/lo split) ----------
// exp(-acosh(x)) = 1/(x + sqrt(x^2-1)); /1.000001 tau factor <=1e-5 rel.
// Output is u8 fixed-point round(C*255): for C in [0,1] the absolute error
// (<=1/510 ~ 0.002) matches bf16's ulp near 1.0, and C==1.0 (the clamped
// ~half of all entries) is exact. This makes C 32 MiB = fits aggregate LDS.
#define LDP 136

__launch_bounds__(256, 2)
__global__ void coupling_kernel(const __hip_bfloat16* __restrict__ Ehi,
                                const __hip_bfloat16* __restrict__ Elo,
                                unsigned char* __restrict__ C) {
    __shared__ __hip_bfloat16 Ah[64 * LDP];
    __shared__ __hip_bfloat16 Al[64 * LDP];
    __shared__ __hip_bfloat16 Bh[64 * LDP];
    __shared__ __hip_bfloat16 Bl[64 * LDP];

    const int b  = blockIdx.z;
    const int n0 = blockIdx.y * 64;
    const int m0 = blockIdx.x * 64;
    const int tid = threadIdx.x;

    const __hip_bfloat16* aHsrc = Ehi + ((size_t)b * NN + n0) * DD;
    const __hip_bfloat16* aLsrc = Elo + ((size_t)b * NN + n0) * DD;
    const __hip_bfloat16* bHsrc = Ehi + ((size_t)b * NN + m0) * DD;
    const __hip_bfloat16* bLsrc = Elo + ((size_t)b * NN + m0) * DD;

    #pragma unroll
    for (int i = 0; i < 4; ++i) {
        int c   = tid + 256 * i;
        int row = c >> 4;
        int col = (c & 15) * 8;
        *(uint4*)(Ah + row * LDP + col) = *(const uint4*)(aHsrc + row * DD + col);
        *(uint4*)(Al + row * LDP + col) = *(const uint4*)(aLsrc + row * DD + col);
        *(uint4*)(Bh + row * LDP + col) = *(const uint4*)(bHsrc + row * DD + col);
        *(uint4*)(Bl + row * LDP + col) = *(const uint4*)(bLsrc + row * DD + col);
    }
    __syncthreads();

    const int wave = tid >> 6;
    const int lane = tid & 63;
    const int l16  = lane & 15;
    const int quad = lane >> 4;

    floatx4 acc[4] = {floatx4{0,0,0,0}, floatx4{0,0,0,0},
                      floatx4{0,0,0,0}, floatx4{0,0,0,0}};

    const int arow = wave * 16 + l16;
    #pragma unroll
    for (int kt = 0; kt < 4; ++kt) {
        const int ko = kt * 32 + quad * 8;
        short8 ah = *(const short8*)(Ah + arow * LDP + ko);
        short8 al = *(const short8*)(Al + arow * LDP + ko);
        #pragma unroll
        for (int c = 0; c < 4; ++c) {
            const int brow = c * 16 + l16;
            short8 bh = *(const short8*)(Bh + brow * LDP + ko);
            short8 bl = *(const short8*)(Bl + brow * LDP + ko);
            acc[c] = __builtin_amdgcn_mfma_f32_16x16x32_bf16(ah, bh, acc[c], 0, 0, 0);
            acc[c] = __builtin_amdgcn_mfma_f32_16x16x32_bf16(ah, bl, acc[c], 0, 0, 0);
            acc[c] = __builtin_amdgcn_mfma_f32_16x16x32_bf16(al, bh, acc[c], 0, 0, 0);
        }
    }

    float tn2[4];
    #pragma unroll
    for (int i = 0; i < 4; ++i) {
        int r = wave * 16 + quad * 4 + i;
        tn2[i] = 2.0f * (__bfloat162float(Ah[r * LDP]) + __bfloat162float(Al[r * LDP]));
    }
    #pragma unroll
    for (int c = 0; c < 4; ++c) {
        int br = c * 16 + l16;
        float tm = __bfloat162float(Bh[br * LDP]) + __bfloat162float(Bl[br * LDP]);
        size_t base = ((size_t)b * NN + n0 + wave * 16 + quad * 4) * (size_t)NN
                      + m0 + c * 16 + l16;
        #pragma unroll
        for (int i = 0; i < 4; ++i) {
            float g   = acc[c][i];
            float arg = fmaxf(fmaf(tn2[i], tm, -g), 1.0f + 1e-7f);
            float s   = sqrtf(fmaf(arg, arg, -1.0f));
            float cp  = __builtin_amdgcn_rcpf(arg + s);
            float cv  = fminf(cp, 1.0f);
            C[base + (size_t)i * NN] = (unsigned char)(cv * 255.0f + 0.5f);
        }
    }
}

// ---------------- K2: persistent kernel, C resident in LDS -----------------
// 256 blocks (1/CU) x 512 threads (8 waves). Each block owns 64 rows of one
// batch, held in LDS as u8 (64 x 2048 B = 128 KiB) + 18 KiB cs table =
// 146.5 KiB <= 160 KiB/CU. C read from global EXACTLY ONCE (32 MiB); every
// step is LDS + VALU only. No big register arrays -> no spill (rounds 1-7:
// allocator hard-caps arch VGPRs at 128 for this kernel at every geometry).
// Per-batch barriers (32 blocks each, 256B-padded counters).

#define CSPAD(m) ((m) + ((m) >> 3))   // +1 float2 pad per 8: lane stride 72B

__launch_bounds__(512, 1)
__global__ void persist_kernel(const unsigned char* __restrict__ C8,
                               const float* __restrict__ theta0,
                               float* __restrict__ thA,
                               float* __restrict__ thB,
                               float* __restrict__ outp,
                               const float* __restrict__ omega,
                               unsigned* __restrict__ bar) {
    __shared__ unsigned char Cl[64 * NN];     // 128 KiB: this block's 64 rows
    __shared__ float2 cs[NN + (NN >> 3)];     // 18 KiB padded cos/sin table

    const int tid  = threadIdx.x;
    const int lane = tid & 63;
    const int wave = tid >> 6;                 // 0..7
    const int b    = blockIdx.x >> 5;          // batch (32 blocks per batch)
    const int rg   = blockIdx.x & 31;          // row group within batch
    const int row0 = rg * 64;                  // this block's first row

    // ---- prologue: copy this block's 64 u8 rows (contiguous 128 KiB) ------
    {
        const uint4* src = (const uint4*)(C8 + ((size_t)b * NN + row0) * (size_t)NN);
        uint4* dst = (uint4*)Cl;
        #pragma unroll
        for (int it = 0; it < 16; ++it)
            dst[it * 512 + tid] = src[it * 512 + tid];
    }
    unsigned* mybar = bar + b * 64;            // 256B-spaced per-batch counter

    const float* cur = theta0;
    for (int s = 0; s < NSTEPS; ++s) {
        const float* th_b = cur + b * NN;

        // ---- cos/sin table for this batch's 2048 thetas (padded LDS) ----
        #pragma unroll
        for (int i = 0; i < 4; ++i) {
            int m = tid + 512 * i;
            float sv, cv;
            __sincosf(th_b[m], &sv, &cv);
            cs[CSPAD(m)] = make_float2(cv, sv);
        }
        __syncthreads();   // cs ready (and on s==0: Cl copy visible to all)

        // ---- MAC: 8 rows/wave x 32 cols/lane, C from LDS (u8) ----
        float a0[8], a1[8], s0[8], s1[8];
        #pragma unroll
        for (int r = 0; r < 8; ++r) { a0[r] = a1[r] = s0[r] = s1[r] = 0.f; }

        #pragma unroll
        for (int j = 0; j < 4; ++j) {
            float cc8[8], ss8[8];              // 1/255 scale folded in
            int p0 = CSPAD(j * 512 + lane * 8);
            #pragma unroll
            for (int i = 0; i < 8; ++i) {
                float2 v = cs[p0 + i];
                cc8[i] = v.x * INV255;
                ss8[i] = v.y * INV255;
            }
            const unsigned char* cb = Cl + (wave * 8) * NN + j * 512 + lane * 8;
            #pragma unroll
            for (int r = 0; r < 8; ++r) {
                uint2 d = *(const uint2*)(cb + r * NN);   // 8 u8 cols
                #pragma unroll
                for (int k = 0; k < 4; ++k) {
                    float f0 = (float)((d.x >> (8 * k)) & 0xffu);  // v_cvt_f32_ubyte
                    float f1 = (float)((d.y >> (8 * k)) & 0xffu);
                    a0[r] = fmaf(f0, cc8[k],     a0[r]);
                    s0[r] = fmaf(f0, ss8[k],     s0[r]);
                    a1[r] = fmaf(f1, cc8[4 + k], a1[r]);
                    s1[r] = fmaf(f1, ss8[4 + k], s1[r]);
                }
            }
        }

        float sumc[8], sums[8];
        #pragma unroll
        for (int r = 0; r < 8; ++r) {
            sumc[r] = a0[r] + a1[r];
            sums[r] = s0[r] + s1[r];
        }

        // ---- 64-lane butterfly reduce ----
        #pragma unroll
        for (int r = 0; r < 8; ++r) {
            #pragma unroll
            for (int off = 32; off >= 1; off >>= 1) {
                sumc[r] += __shfl_xor(sumc[r], off, 64);
                sums[r] += __shfl_xor(sums[r], off, 64);
            }
        }

        // ---- theta update for this wave's 8 rows ----
        float* nxt = (s == NSTEPS - 1) ? outp : ((s & 1) ? thB : thA);
        #pragma unroll
        for (int r = 0; r < 8; ++r) {
            if (lane == r) {
                int n = row0 + wave * 8 + r;
                float2 csn = cs[CSPAD(n)];
                float sum  = csn.y * sumc[r] - csn.x * sums[r];
                float th   = th_b[n];
                float dth  = omega[n] + (1.0f / NN) * sum;
                nxt[b * NN + n] = fmodf(th + DT_F * dth, TWO_PI_F);
            }
        }

        // ---- per-batch barrier (32 blocks) ----
        if (s != NSTEPS - 1) {
            __threadfence();
            __syncthreads();
            if (tid == 0) {
                __hip_atomic_fetch_add(mybar, 1u, __ATOMIC_RELEASE,
                                       __HIP_MEMORY_SCOPE_AGENT);
                while (__hip_atomic_load(mybar, __ATOMIC_ACQUIRE,
                                         __HIP_MEMORY_SCOPE_AGENT)
                       < (unsigned)BLK_PER_BATCH * (unsigned)(s + 1))
                    __builtin_amdgcn_s_sleep(2);
            }
            __syncthreads();
            __threadfence();
            cur = (s & 1) ? thB : thA;
        }
    }
}

// ---------------- launch ----------------------------------------------------
extern "C" void kernel_launch(void* const* d_in, const int* in_sizes, int n_in,
                              void* d_out, int out_size, void* d_ws, size_t ws_size,
                              hipStream_t stream) {
    const float* theta0 = (const float*)d_in[0];
    const float* emb    = (const float*)d_in[1];
    const float* omega  = (const float*)d_in[2];
    float* out = (float*)d_out;

    char* ws = (char*)d_ws;
    unsigned char* C8   = (unsigned char*)ws;                        // 32 MiB
    __hip_bfloat16* Ehi = (__hip_bfloat16*)(ws + 33554432);          // 4 MiB
    __hip_bfloat16* Elo = (__hip_bfloat16*)(ws + 37748736);          // 4 MiB
    float* tA = (float*)(ws + 41943040);                             // 64 KiB
    float* tB = (float*)(ws + 42008576);                             // 64 KiB
    unsigned* bar = (unsigned*)(ws + 42074112);                      // 2 KiB

    split_kernel<<<(BB * NN * DD) / 256, 256, 0, stream>>>(emb, Ehi, Elo, bar);

    dim3 g1(NN / 64, NN / 64, BB);
    coupling_kernel<<<g1, 256, 0, stream>>>(Ehi, Elo, C8);

    const unsigned char* Cc = C8;
    void* kargs[] = { (void*)&Cc, (void*)&theta0, (void*)&tA, (void*)&tB,
                      (void*)&out, (void*)&omega, (void*)&bar };
    hipLaunchCooperativeKernel((void*)persist_kernel, dim3(PBLK), dim3(512),
                               kargs, 0, stream);
}